// Round 5
// baseline (194.573 us; speedup 1.0000x reference)
//
#include <hip/hip_runtime.h>
#include <cstdint>
#include <cstddef>

#define NB 2
#define NL 2048
#define ND 1024
#define NH 16
#define NHD 64
#define BHNL (NB * NH * NL)

typedef __bf16 bf16x8 __attribute__((ext_vector_type(8)));
typedef float f32x4 __attribute__((ext_vector_type(4)));

__device__ __forceinline__ void gload16(const void* g, void* l) {
  __builtin_amdgcn_global_load_lds(
      (__attribute__((address_space(1))) uint32_t*)(uintptr_t)g,
      (__attribute__((address_space(3))) uint32_t*)l, 16, 0, 0);
}

// ---------------- fused 3x elementwise f32 -> bf16 ----------------
__global__ __launch_bounds__(256) void cvt3_f32_bf16(
    const float* __restrict__ s0, const float* __restrict__ s1,
    const float* __restrict__ s2, __bf16* __restrict__ d0,
    __bf16* __restrict__ d1, __bf16* __restrict__ d2, int n4) {
  const float* src;
  __bf16* dst;
  switch (blockIdx.y) {
    case 0: src = s0; dst = d0; break;
    case 1: src = s1; dst = d1; break;
    default: src = s2; dst = d2; break;
  }
  int i = blockIdx.x * 256 + threadIdx.x;
  if (i >= n4) return;
  float4 f = reinterpret_cast<const float4*>(src)[i];
  ushort4 u;
  u.x = __builtin_bit_cast(unsigned short, (__bf16)f.x);
  u.y = __builtin_bit_cast(unsigned short, (__bf16)f.y);
  u.z = __builtin_bit_cast(unsigned short, (__bf16)f.z);
  u.w = __builtin_bit_cast(unsigned short, (__bf16)f.w);
  reinterpret_cast<ushort4*>(dst)[i] = u;
}

// ---------------- 4x weight transpose+convert: Wt[n][k] = bf16(W[k][n]) ----------------
__global__ __launch_bounds__(256) void transpose_cvt4(
    const float* __restrict__ W0, const float* __restrict__ W1,
    const float* __restrict__ W2, const float* __restrict__ W3,
    __bf16* __restrict__ T0, __bf16* __restrict__ T1,
    __bf16* __restrict__ T2, __bf16* __restrict__ T3) {
  const float* W;
  __bf16* T;
  switch (blockIdx.z) {
    case 0: W = W0; T = T0; break;
    case 1: W = W1; T = T1; break;
    case 2: W = W2; T = T2; break;
    default: W = W3; T = T3; break;
  }
  __shared__ float tile[32][33];
  int tx = threadIdx.x, ty = threadIdx.y;
  int x0 = blockIdx.x * 32, y0 = blockIdx.y * 32;
#pragma unroll
  for (int r = 0; r < 4; r++)
    tile[ty + r * 8][tx] = W[(y0 + ty + r * 8) * ND + x0 + tx];
  __syncthreads();
#pragma unroll
  for (int r = 0; r < 4; r++)
    T[(x0 + ty + r * 8) * ND + y0 + tx] = (__bf16)tile[tx][ty + r * 8];
}

// ---------------- distance bins, 4 k per thread ----------------
__global__ __launch_bounds__(256) void bins_kernel(const float* __restrict__ pos,
                                                   unsigned char* __restrict__ bins) {
  int k0 = (blockIdx.x * 256 + threadIdx.x) * 4;
  int q = blockIdx.y;
  int b = blockIdx.z;
  float qx = pos[((size_t)b * NL + q) * 3 + 0];
  float qy = pos[((size_t)b * NL + q) * 3 + 1];
  float qz = pos[((size_t)b * NL + q) * 3 + 2];
  const float* kp = pos + ((size_t)b * NL + k0) * 3;
  float4 p0 = *(const float4*)(kp + 0);
  float4 p1 = *(const float4*)(kp + 4);
  float4 p2 = *(const float4*)(kp + 8);
  float kx[4] = {p0.x, p0.w, p1.z, p2.y};
  float ky[4] = {p0.y, p1.x, p1.w, p2.z};
  float kz[4] = {p0.z, p1.y, p2.x, p2.w};
  uchar4 out;
  unsigned char* o = (unsigned char*)&out;
#pragma unroll
  for (int j = 0; j < 4; j++) {
    float dx = qx - kx[j], dy = qy - ky[j], dz = qz - kz[j];
    float dist = sqrtf(dx * dx + dy * dy + dz * dz);
    float t = (dist / 5.0f) * 32.0f;  // match reference op order
    int bin = (int)t;
    bin = bin > 32 ? 32 : bin;
    o[j] = (unsigned char)bin;
  }
  *(uchar4*)(bins + ((size_t)b * NL + q) * NL + k0) = out;
}

// ---------------- merged QKV projection GEMM, 128x128 tile, XCD-swizzled -------
__global__ __launch_bounds__(256) void gemm_qkv(
    const __bf16* __restrict__ Aq, const __bf16* __restrict__ Ak,
    const __bf16* __restrict__ Av, const __bf16* __restrict__ Wqt,
    const __bf16* __restrict__ Wkt, const __bf16* __restrict__ Wvt,
    const float* __restrict__ bq, const float* __restrict__ bk,
    const float* __restrict__ bv, __bf16* __restrict__ Qp,
    __bf16* __restrict__ Kp, __bf16* __restrict__ Vtp) {
  __shared__ __bf16 As[128 * 64];
  __shared__ __bf16 Bs[128 * 64];
  const int tid = threadIdx.x;
  const int lane = tid & 63;
  const int wave = tid >> 6;
  // bijective XCD swizzle: 768 blocks, 96 contiguous work items per XCD
  const int wid = (blockIdx.x & 7) * 96 + (blockIdx.x >> 3);
  const int z = wid >> 8;
  const int r = wid & 255;
  const int bm = r & 31;
  const int bn = r >> 5;
  const __bf16* A = (z == 0) ? Aq : (z == 1) ? Ak : Av;
  const __bf16* Bt = (z == 0) ? Wqt : (z == 1) ? Wkt : Wvt;
  const float* bias = (z == 0) ? bq : (z == 1) ? bk : bv;
  __bf16* C = (z == 0) ? Qp : (z == 1) ? Kp : Vtp;

  const int wm = (wave >> 1) * 64;
  const int wn = (wave & 1) * 64;
  f32x4 acc[4][4] = {};
  const __bf16* Abase = A + (size_t)(bm * 128) * ND;
  const __bf16* Bbase = Bt + (size_t)(bn * 128) * ND;

  for (int kt = 0; kt < ND; kt += 64) {
#pragma unroll
    for (int i = 0; i < 4; i++) {
      int lin = i * 256 + tid;
      int row = lin >> 3;
      int c = (lin & 7) ^ (row & 7);
      gload16(Abase + (size_t)row * ND + kt + c * 8, (char*)As + lin * 16);
    }
#pragma unroll
    for (int i = 0; i < 4; i++) {
      int lin = i * 256 + tid;
      int row = lin >> 3;
      int c = (lin & 7) ^ (row & 7);
      gload16(Bbase + (size_t)row * ND + kt + c * 8, (char*)Bs + lin * 16);
    }
    __syncthreads();
#pragma unroll
    for (int kk = 0; kk < 2; kk++) {
      const int cb = kk * 4 + (lane >> 4);
      bf16x8 af[4], bfr[4];
#pragma unroll
      for (int mf = 0; mf < 4; mf++) {
        int rr = wm + mf * 16 + (lane & 15);
        af[mf] = *(const bf16x8*)((const char*)As + rr * 128 + ((cb ^ (rr & 7)) << 4));
      }
#pragma unroll
      for (int nf = 0; nf < 4; nf++) {
        int rr = wn + nf * 16 + (lane & 15);
        bfr[nf] = *(const bf16x8*)((const char*)Bs + rr * 128 + ((cb ^ (rr & 7)) << 4));
      }
      __builtin_amdgcn_s_setprio(1);
#pragma unroll
      for (int mf = 0; mf < 4; mf++)
#pragma unroll
        for (int nf = 0; nf < 4; nf++)
          acc[mf][nf] = __builtin_amdgcn_mfma_f32_16x16x32_bf16(af[mf], bfr[nf],
                                                                acc[mf][nf], 0, 0, 0);
      __builtin_amdgcn_s_setprio(0);
    }
    __syncthreads();
  }

  const int rbase = (lane >> 4) << 2;
  const int cbase = lane & 15;
  if (z < 2) {
#pragma unroll
    for (int mf = 0; mf < 4; mf++)
#pragma unroll
      for (int nf = 0; nf < 4; nf++) {
        int m0 = bm * 128 + wm + mf * 16 + rbase;
        int n = bn * 128 + wn + nf * 16 + cbase;
        float bvv = bias[n];
        int b = m0 >> 11, ls = m0 & (NL - 1);
        int h = n >> 6, d = n & 63;
        __bf16* base = C + ((size_t)((b * NH + h) * NL + ls)) * NHD + d;
#pragma unroll
        for (int j = 0; j < 4; j++)
          base[(size_t)j * NHD] = (__bf16)(acc[mf][nf][j] + bvv);
      }
  } else {
#pragma unroll
    for (int mf = 0; mf < 4; mf++)
#pragma unroll
      for (int nf = 0; nf < 4; nf++) {
        int m0 = bm * 128 + wm + mf * 16 + rbase;
        int n = bn * 128 + wn + nf * 16 + cbase;
        float bvv = bias[n];
        int b = m0 >> 11, ls = m0 & (NL - 1);
        int h = n >> 6, d = n & 63;
        ushort4 u;
        u.x = __builtin_bit_cast(unsigned short, (__bf16)(acc[mf][nf][0] + bvv));
        u.y = __builtin_bit_cast(unsigned short, (__bf16)(acc[mf][nf][1] + bvv));
        u.z = __builtin_bit_cast(unsigned short, (__bf16)(acc[mf][nf][2] + bvv));
        u.w = __builtin_bit_cast(unsigned short, (__bf16)(acc[mf][nf][3] + bvv));
        *(ushort4*)(C + ((size_t)((b * NH + h) * NHD + d)) * NL + ls) = u;
      }
  }
}

// ---------------- output projection GEMM (128x128 tile, f32 out) ----------------
__global__ __launch_bounds__(256) void gemm_out(
    const __bf16* __restrict__ A, const __bf16* __restrict__ Bt,
    const float* __restrict__ bias, float* __restrict__ C) {
  __shared__ __bf16 As[128 * 64];
  __shared__ __bf16 Bs[128 * 64];
  const int tid = threadIdx.x;
  const int lane = tid & 63;
  const int wave = tid >> 6;
  const int bm = blockIdx.x & 31;
  const int bn = blockIdx.x >> 5;
  const int wm = (wave >> 1) * 64;
  const int wn = (wave & 1) * 64;
  f32x4 acc[4][4] = {};
  const __bf16* Abase = A + (size_t)(bm * 128) * ND;
  const __bf16* Bbase = Bt + (size_t)(bn * 128) * ND;

  for (int kt = 0; kt < ND; kt += 64) {
#pragma unroll
    for (int i = 0; i < 4; i++) {
      int lin = i * 256 + tid;
      int row = lin >> 3;
      int c = (lin & 7) ^ (row & 7);
      gload16(Abase + (size_t)row * ND + kt + c * 8, (char*)As + lin * 16);
    }
#pragma unroll
    for (int i = 0; i < 4; i++) {
      int lin = i * 256 + tid;
      int row = lin >> 3;
      int c = (lin & 7) ^ (row & 7);
      gload16(Bbase + (size_t)row * ND + kt + c * 8, (char*)Bs + lin * 16);
    }
    __syncthreads();
#pragma unroll
    for (int kk = 0; kk < 2; kk++) {
      const int cb = kk * 4 + (lane >> 4);
      bf16x8 af[4], bfr[4];
#pragma unroll
      for (int mf = 0; mf < 4; mf++) {
        int rr = wm + mf * 16 + (lane & 15);
        af[mf] = *(const bf16x8*)((const char*)As + rr * 128 + ((cb ^ (rr & 7)) << 4));
      }
#pragma unroll
      for (int nf = 0; nf < 4; nf++) {
        int rr = wn + nf * 16 + (lane & 15);
        bfr[nf] = *(const bf16x8*)((const char*)Bs + rr * 128 + ((cb ^ (rr & 7)) << 4));
      }
      __builtin_amdgcn_s_setprio(1);
#pragma unroll
      for (int mf = 0; mf < 4; mf++)
#pragma unroll
        for (int nf = 0; nf < 4; nf++)
          acc[mf][nf] = __builtin_amdgcn_mfma_f32_16x16x32_bf16(af[mf], bfr[nf],
                                                                acc[mf][nf], 0, 0, 0);
      __builtin_amdgcn_s_setprio(0);
    }
    __syncthreads();
  }

  const int rbase = (lane >> 4) << 2;
  const int cbase = lane & 15;
#pragma unroll
  for (int mf = 0; mf < 4; mf++)
#pragma unroll
    for (int nf = 0; nf < 4; nf++) {
      int m0 = bm * 128 + wm + mf * 16 + rbase;
      int n = bn * 128 + wn + nf * 16 + cbase;
      float bvv = bias[n];
#pragma unroll
      for (int j = 0; j < 4; j++)
        C[(size_t)(m0 + j) * ND + n] = acc[mf][nf][j] + bvv;
    }
}

// ---------------- flash attention: 32 q/wave, k-split, conflict-free table ------
__global__ __launch_bounds__(256, 4) void attn_kernel(
    const __bf16* __restrict__ Q, const __bf16* __restrict__ K,
    const __bf16* __restrict__ Vt, const unsigned char* __restrict__ bins,
    const float* __restrict__ emb, float* __restrict__ O0,
    float* __restrict__ O1, float* __restrict__ lsums) {
  __shared__ __bf16 Ks[64 * 64];
  __shared__ __bf16 Vs[64 * 64];
  __shared__ __bf16 Ps[4][32 * 64];
  __shared__ float embr[33 * 32];  // 32 replicas, indexed by lane&31 -> conflict-free
  const int tid = threadIdx.x;
  const int lane = tid & 63;
  const int wave = tid >> 6;
  const int qt = blockIdx.x & 15;
  const int h = (blockIdx.x >> 4) & 15;
  const int b = (blockIdx.x >> 8) & 1;
  const int s = blockIdx.x >> 9;
  for (int idx = tid; idx < 33 * 32; idx += 256)
    embr[idx] = emb[(idx >> 5) * NH + h] * 1.44269504f;
  const int lr = lane & 15;
  const int lg = lane >> 4;
  const int q0 = qt * 128 + wave * 32;
  const int bh = b * NH + h;
  const float* embrl = embr + (lane & 31);

  // Q fragments: [kk][qh]
  const __bf16* Qb0 = Q + ((size_t)(bh * NL + q0 + lr)) * NHD + lg * 8;
  bf16x8 qf[2][2];
  qf[0][0] = *(const bf16x8*)(Qb0);
  qf[1][0] = *(const bf16x8*)(Qb0 + 32);
  qf[0][1] = *(const bf16x8*)(Qb0 + 16 * NHD);
  qf[1][1] = *(const bf16x8*)(Qb0 + 16 * NHD + 32);

  const unsigned char* binq0 =
      bins + ((size_t)b * NL + (q0 + lr)) * NL + s * 1024 + lg * 4;
  const unsigned char* binq1 = binq0 + (size_t)16 * NL;

  float lsum[2] = {0.f, 0.f};
  f32x4 oacc[4][2] = {};
  const __bf16* Kbase = K + ((size_t)(bh * NL + s * 1024)) * NHD;
  const __bf16* Vbase = Vt + ((size_t)(bh * NHD)) * NL + s * 1024;
  char* psw = (char*)&Ps[wave][0];
  const int pswz = (lr & 7) << 4;

  for (int t = 0; t < 16; t++) {
    const int kt = t * 64;
    // stage K,V tiles
#pragma unroll
    for (int i = 0; i < 2; i++) {
      int lin = i * 256 + tid;
      int row = lin >> 3;
      int c = (lin & 7) ^ (row & 7);
      gload16(Kbase + (size_t)(kt + row) * NHD + c * 8, (char*)Ks + lin * 16);
      gload16(Vbase + (size_t)row * NL + kt + c * 8, (char*)Vs + lin * 16);
    }
    // bins prefetch (global, independent of LDS)
    uint32_t bv[4][2];
#pragma unroll
    for (int kf = 0; kf < 4; kf++) {
      bv[kf][0] = *(const uint32_t*)(binq0 + kt + kf * 16);
      bv[kf][1] = *(const uint32_t*)(binq1 + kt + kf * 16);
    }
    __syncthreads();

    // QK^T + softmax, processed in kf-pairs (keeps VGPR peak low)
#pragma unroll
    for (int kfp = 0; kfp < 2; kfp++) {
      f32x4 sacc[2][2] = {};
#pragma unroll
      for (int kk = 0; kk < 2; kk++) {
        const int cb = kk * 4 + lg;
        bf16x8 kb[2];
#pragma unroll
        for (int k2 = 0; k2 < 2; k2++) {
          int rr = (kfp * 2 + k2) * 16 + lr;
          kb[k2] =
              *(const bf16x8*)((const char*)Ks + rr * 128 + ((cb ^ (rr & 7)) << 4));
        }
        __builtin_amdgcn_s_setprio(1);
#pragma unroll
        for (int qh = 0; qh < 2; qh++)
#pragma unroll
          for (int k2 = 0; k2 < 2; k2++)
            sacc[k2][qh] = __builtin_amdgcn_mfma_f32_16x16x32_bf16(
                kb[k2], qf[kk][qh], sacc[k2][qh], 0, 0, 0);
        __builtin_amdgcn_s_setprio(0);
      }
#pragma unroll
      for (int k2 = 0; k2 < 2; k2++) {
        const int kf = kfp * 2 + k2;
#pragma unroll
        for (int qh = 0; qh < 2; qh++) {
          float p[4];
#pragma unroll
          for (int j = 0; j < 4; j++) {
            int bin = (bv[kf][qh] >> (8 * j)) & 255;
            float w = embrl[bin << 5];
            p[j] = __builtin_amdgcn_exp2f(fmaf(sacc[k2][qh][j], 0.1803368801f, w));
            lsum[qh] += p[j];
          }
          ushort4 u;
          u.x = __builtin_bit_cast(unsigned short, (__bf16)p[0]);
          u.y = __builtin_bit_cast(unsigned short, (__bf16)p[1]);
          u.z = __builtin_bit_cast(unsigned short, (__bf16)p[2]);
          u.w = __builtin_bit_cast(unsigned short, (__bf16)p[3]);
          int row = qh * 16 + lr;
          int col = (kf * 32 + lg * 8) ^ pswz;
          *(ushort4*)(psw + row * 128 + col) = u;
        }
      }
    }

    // PV: vb shared across both q-halves
#pragma unroll
    for (int kk = 0; kk < 2; kk++) {
      const int cb = kk * 4 + lg;
      bf16x8 vb[4];
#pragma unroll
      for (int df = 0; df < 4; df++) {
        int rr = df * 16 + lr;
        vb[df] =
            *(const bf16x8*)((const char*)Vs + rr * 128 + ((cb ^ (rr & 7)) << 4));
      }
      bf16x8 pa[2];
#pragma unroll
      for (int qh = 0; qh < 2; qh++)
        pa[qh] = *(const bf16x8*)(psw + (qh * 16 + lr) * 128 +
                                  ((kk * 64 + lg * 16) ^ pswz));
      __builtin_amdgcn_s_setprio(1);
#pragma unroll
      for (int qh = 0; qh < 2; qh++)
#pragma unroll
        for (int df = 0; df < 4; df++)
          oacc[df][qh] = __builtin_amdgcn_mfma_f32_16x16x32_bf16(
              vb[df], pa[qh], oacc[df][qh], 0, 0, 0);
      __builtin_amdgcn_s_setprio(0);
    }
    __syncthreads();
  }

  // epilogue: unnormalized O + lsum partials for this k-half
  float* Op = s ? O1 : O0;
  float* lsp = lsums + s * BHNL;
#pragma unroll
  for (int qh = 0; qh < 2; qh++) {
    float l = lsum[qh];
    l += __shfl_xor(l, 16, 64);
    l += __shfl_xor(l, 32, 64);
    int qrow = q0 + qh * 16 + lr;
    size_t r = (size_t)bh * NL + qrow;
    if (lg == 0) lsp[r] = l;
    float* ob = Op + r * NHD + lg * 4;
#pragma unroll
    for (int df = 0; df < 4; df++) *(f32x4*)(ob + df * 16) = oacc[df][qh];
  }
}

// ---------------- combine: O = (O0+O1)/(l0+l1), write bf16 [b,l,h*d] ------------
__global__ __launch_bounds__(256) void combine_kernel(
    const float* __restrict__ O0, const float* __restrict__ O1,
    const float* __restrict__ ls, __bf16* __restrict__ outb) {
  int gid = blockIdx.x * 256 + threadIdx.x;  // BHNL*16 threads
  int row = gid >> 4;
  int d4 = (gid & 15) << 2;
  float l = ls[row] + ls[BHNL + row];
  float inv = 1.0f / l;
  f32x4 a = *(const f32x4*)(O0 + (size_t)row * NHD + d4);
  f32x4 c = *(const f32x4*)(O1 + (size_t)row * NHD + d4);
  int bh = row >> 11, q = row & (NL - 1);
  int b = bh >> 4, h = bh & 15;
  ushort4 u;
  u.x = __builtin_bit_cast(unsigned short, (__bf16)((a[0] + c[0]) * inv));
  u.y = __builtin_bit_cast(unsigned short, (__bf16)((a[1] + c[1]) * inv));
  u.z = __builtin_bit_cast(unsigned short, (__bf16)((a[2] + c[2]) * inv));
  u.w = __builtin_bit_cast(unsigned short, (__bf16)((a[3] + c[3]) * inv));
  *(ushort4*)(outb + ((size_t)(b * NL + q)) * ND + h * NHD + d4) = u;
}

extern "C" void kernel_launch(void* const* d_in, const int* in_sizes, int n_in,
                              void* d_out, int out_size, void* d_ws, size_t ws_size,
                              hipStream_t stream) {
  const float* query = (const float*)d_in[0];
  const float* key = (const float*)d_in[1];
  const float* value = (const float*)d_in[2];
  const float* pos = (const float*)d_in[3];
  const float* Wq = (const float*)d_in[4];
  const float* bq = (const float*)d_in[5];
  const float* Wk = (const float*)d_in[6];
  const float* bk = (const float*)d_in[7];
  const float* Wv = (const float*)d_in[8];
  const float* bv = (const float*)d_in[9];
  const float* Wo = (const float*)d_in[10];
  const float* bo = (const float*)d_in[11];
  const float* emb = (const float*)d_in[12];

  if (ws_size < (64ull << 20)) return;  // need 64MB scratch
  char* ws = (char*)d_ws;
  const size_t MB = 1ull << 20;
  __bf16* qb = (__bf16*)(ws + 0 * MB);
  __bf16* kb = (__bf16*)(ws + 8 * MB);
  __bf16* vb = (__bf16*)(ws + 16 * MB);
  __bf16* Wq_t = (__bf16*)(ws + 24 * MB);
  __bf16* Wk_t = (__bf16*)(ws + 26 * MB);
  __bf16* Wv_t = (__bf16*)(ws + 28 * MB);
  __bf16* Wo_t = (__bf16*)(ws + 30 * MB);
  __bf16* Qp = (__bf16*)(ws + 32 * MB);
  __bf16* Kp = (__bf16*)(ws + 40 * MB);
  __bf16* Vtp = (__bf16*)(ws + 48 * MB);
  unsigned char* binsb = (unsigned char*)(ws + 56 * MB);
  // after gemm_qkv, qb/kb (0-16MB) and Wq_t (24-26MB) are dead:
  float* Opart0 = (float*)(ws + 0 * MB);       // 16MB f32, over qb+kb
  float* Opart1 = (float*)d_out;               // 16MB f32, free until gemm_out
  float* lsums = (float*)(ws + 24 * MB);       // 2*BHNL f32 = 512KB, over Wq_t
  __bf16* attnb = (__bf16*)(ws + 16 * MB);     // 8MB bf16, over vb (dead post-qkv)

  const int n4 = NB * NL * ND / 4;
  cvt3_f32_bf16<<<dim3(n4 / 256, 3), 256, 0, stream>>>(query, key, value, qb, kb, vb,
                                                       n4);
  transpose_cvt4<<<dim3(32, 32, 4), dim3(32, 8), 0, stream>>>(Wq, Wk, Wv, Wo, Wq_t,
                                                              Wk_t, Wv_t, Wo_t);
  bins_kernel<<<dim3(NL / 1024, NL, NB), 256, 0, stream>>>(pos, binsb);

  gemm_qkv<<<3 * 256, 256, 0, stream>>>(qb, kb, vb, Wq_t, Wk_t, Wv_t, bq, bk, bv, Qp,
                                        Kp, Vtp);

  attn_kernel<<<NB * NH * 16 * 2, 256, 0, stream>>>(Qp, Kp, Vtp, binsb, emb, Opart0,
                                                    Opart1, lsums);

  combine_kernel<<<(BHNL * 16) / 256, 256, 0, stream>>>(Opart0, Opart1, lsums, attnb);

  gemm_out<<<256, 256, 0, stream>>>(attnb, Wo_t, bo, (float*)d_out);
}

// Round 6
// 172.491 us; speedup vs baseline: 1.1280x; 1.1280x over previous
//
#include <hip/hip_runtime.h>
#include <cstdint>
#include <cstddef>

#define NB 2
#define NL 2048
#define ND 1024
#define NH 16
#define NHD 64
#define BHNL (NB * NH * NL)

typedef __bf16 bf16x8 __attribute__((ext_vector_type(8)));
typedef float f32x4 __attribute__((ext_vector_type(4)));

__device__ __forceinline__ void gload16(const void* g, void* l) {
  __builtin_amdgcn_global_load_lds(
      (__attribute__((address_space(1))) uint32_t*)(uintptr_t)g,
      (__attribute__((address_space(3))) uint32_t*)l, 16, 0, 0);
}

// ---------------- fused 3x elementwise f32 -> bf16 ----------------
__global__ __launch_bounds__(256) void cvt3_f32_bf16(
    const float* __restrict__ s0, const float* __restrict__ s1,
    const float* __restrict__ s2, __bf16* __restrict__ d0,
    __bf16* __restrict__ d1, __bf16* __restrict__ d2, int n4) {
  const float* src;
  __bf16* dst;
  switch (blockIdx.y) {
    case 0: src = s0; dst = d0; break;
    case 1: src = s1; dst = d1; break;
    default: src = s2; dst = d2; break;
  }
  int i = blockIdx.x * 256 + threadIdx.x;
  if (i >= n4) return;
  float4 f = reinterpret_cast<const float4*>(src)[i];
  ushort4 u;
  u.x = __builtin_bit_cast(unsigned short, (__bf16)f.x);
  u.y = __builtin_bit_cast(unsigned short, (__bf16)f.y);
  u.z = __builtin_bit_cast(unsigned short, (__bf16)f.z);
  u.w = __builtin_bit_cast(unsigned short, (__bf16)f.w);
  reinterpret_cast<ushort4*>(dst)[i] = u;
}

// ---------------- 4x weight transpose+convert: Wt[n][k] = bf16(W[k][n]) ----------------
__global__ __launch_bounds__(256) void transpose_cvt4(
    const float* __restrict__ W0, const float* __restrict__ W1,
    const float* __restrict__ W2, const float* __restrict__ W3,
    __bf16* __restrict__ T0, __bf16* __restrict__ T1,
    __bf16* __restrict__ T2, __bf16* __restrict__ T3) {
  const float* W;
  __bf16* T;
  switch (blockIdx.z) {
    case 0: W = W0; T = T0; break;
    case 1: W = W1; T = T1; break;
    case 2: W = W2; T = T2; break;
    default: W = W3; T = T3; break;
  }
  __shared__ float tile[32][33];
  int tx = threadIdx.x, ty = threadIdx.y;
  int x0 = blockIdx.x * 32, y0 = blockIdx.y * 32;
#pragma unroll
  for (int r = 0; r < 4; r++)
    tile[ty + r * 8][tx] = W[(y0 + ty + r * 8) * ND + x0 + tx];
  __syncthreads();
#pragma unroll
  for (int r = 0; r < 4; r++)
    T[(x0 + ty + r * 8) * ND + y0 + tx] = (__bf16)tile[tx][ty + r * 8];
}

// ---------------- distance bins, 4 k per thread ----------------
__global__ __launch_bounds__(256) void bins_kernel(const float* __restrict__ pos,
                                                   unsigned char* __restrict__ bins) {
  int k0 = (blockIdx.x * 256 + threadIdx.x) * 4;
  int q = blockIdx.y;
  int b = blockIdx.z;
  float qx = pos[((size_t)b * NL + q) * 3 + 0];
  float qy = pos[((size_t)b * NL + q) * 3 + 1];
  float qz = pos[((size_t)b * NL + q) * 3 + 2];
  const float* kp = pos + ((size_t)b * NL + k0) * 3;
  float4 p0 = *(const float4*)(kp + 0);
  float4 p1 = *(const float4*)(kp + 4);
  float4 p2 = *(const float4*)(kp + 8);
  float kx[4] = {p0.x, p0.w, p1.z, p2.y};
  float ky[4] = {p0.y, p1.x, p1.w, p2.z};
  float kz[4] = {p0.z, p1.y, p2.x, p2.w};
  uchar4 out;
  unsigned char* o = (unsigned char*)&out;
#pragma unroll
  for (int j = 0; j < 4; j++) {
    float dx = qx - kx[j], dy = qy - ky[j], dz = qz - kz[j];
    float dist = sqrtf(dx * dx + dy * dy + dz * dz);
    float t = (dist / 5.0f) * 32.0f;  // match reference op order
    int bin = (int)t;
    bin = bin > 32 ? 32 : bin;
    o[j] = (unsigned char)bin;
  }
  *(uchar4*)(bins + ((size_t)b * NL + q) * NL + k0) = out;
}

// ---------------- merged QKV projection GEMM, 128x128 tile ----------------
__global__ __launch_bounds__(256) void gemm_qkv(
    const __bf16* __restrict__ Aq, const __bf16* __restrict__ Ak,
    const __bf16* __restrict__ Av, const __bf16* __restrict__ Wqt,
    const __bf16* __restrict__ Wkt, const __bf16* __restrict__ Wvt,
    const float* __restrict__ bq, const float* __restrict__ bk,
    const float* __restrict__ bv, __bf16* __restrict__ Qp,
    __bf16* __restrict__ Kp, __bf16* __restrict__ Vtp) {
  __shared__ __bf16 As[128 * 64];
  __shared__ __bf16 Bs[128 * 64];
  const int tid = threadIdx.x;
  const int lane = tid & 63;
  const int wave = tid >> 6;
  const int z = blockIdx.x >> 8;
  const int r = blockIdx.x & 255;
  const int bm = r & 31;
  const int bn = r >> 5;
  const __bf16* A = (z == 0) ? Aq : (z == 1) ? Ak : Av;
  const __bf16* Bt = (z == 0) ? Wqt : (z == 1) ? Wkt : Wvt;
  const float* bias = (z == 0) ? bq : (z == 1) ? bk : bv;
  __bf16* C = (z == 0) ? Qp : (z == 1) ? Kp : Vtp;

  const int wm = (wave >> 1) * 64;
  const int wn = (wave & 1) * 64;
  f32x4 acc[4][4] = {};
  const __bf16* Abase = A + (size_t)(bm * 128) * ND;
  const __bf16* Bbase = Bt + (size_t)(bn * 128) * ND;

  for (int kt = 0; kt < ND; kt += 64) {
#pragma unroll
    for (int i = 0; i < 4; i++) {
      int lin = i * 256 + tid;
      int row = lin >> 3;
      int c = (lin & 7) ^ (row & 7);
      gload16(Abase + (size_t)row * ND + kt + c * 8, (char*)As + lin * 16);
    }
#pragma unroll
    for (int i = 0; i < 4; i++) {
      int lin = i * 256 + tid;
      int row = lin >> 3;
      int c = (lin & 7) ^ (row & 7);
      gload16(Bbase + (size_t)row * ND + kt + c * 8, (char*)Bs + lin * 16);
    }
    __syncthreads();
#pragma unroll
    for (int kk = 0; kk < 2; kk++) {
      const int cb = kk * 4 + (lane >> 4);
      bf16x8 af[4], bfr[4];
#pragma unroll
      for (int mf = 0; mf < 4; mf++) {
        int rr = wm + mf * 16 + (lane & 15);
        af[mf] = *(const bf16x8*)((const char*)As + rr * 128 + ((cb ^ (rr & 7)) << 4));
      }
#pragma unroll
      for (int nf = 0; nf < 4; nf++) {
        int rr = wn + nf * 16 + (lane & 15);
        bfr[nf] = *(const bf16x8*)((const char*)Bs + rr * 128 + ((cb ^ (rr & 7)) << 4));
      }
      __builtin_amdgcn_s_setprio(1);
#pragma unroll
      for (int mf = 0; mf < 4; mf++)
#pragma unroll
        for (int nf = 0; nf < 4; nf++)
          acc[mf][nf] = __builtin_amdgcn_mfma_f32_16x16x32_bf16(af[mf], bfr[nf],
                                                                acc[mf][nf], 0, 0, 0);
      __builtin_amdgcn_s_setprio(0);
    }
    __syncthreads();
  }

  const int rbase = (lane >> 4) << 2;
  const int cbase = lane & 15;
  if (z < 2) {
#pragma unroll
    for (int mf = 0; mf < 4; mf++)
#pragma unroll
      for (int nf = 0; nf < 4; nf++) {
        int m0 = bm * 128 + wm + mf * 16 + rbase;
        int n = bn * 128 + wn + nf * 16 + cbase;
        float bvv = bias[n];
        int b = m0 >> 11, ls = m0 & (NL - 1);
        int h = n >> 6, d = n & 63;
        __bf16* base = C + ((size_t)((b * NH + h) * NL + ls)) * NHD + d;
#pragma unroll
        for (int j = 0; j < 4; j++)
          base[(size_t)j * NHD] = (__bf16)(acc[mf][nf][j] + bvv);
      }
  } else {
#pragma unroll
    for (int mf = 0; mf < 4; mf++)
#pragma unroll
      for (int nf = 0; nf < 4; nf++) {
        int m0 = bm * 128 + wm + mf * 16 + rbase;
        int n = bn * 128 + wn + nf * 16 + cbase;
        float bvv = bias[n];
        int b = m0 >> 11, ls = m0 & (NL - 1);
        int h = n >> 6, d = n & 63;
        ushort4 u;
        u.x = __builtin_bit_cast(unsigned short, (__bf16)(acc[mf][nf][0] + bvv));
        u.y = __builtin_bit_cast(unsigned short, (__bf16)(acc[mf][nf][1] + bvv));
        u.z = __builtin_bit_cast(unsigned short, (__bf16)(acc[mf][nf][2] + bvv));
        u.w = __builtin_bit_cast(unsigned short, (__bf16)(acc[mf][nf][3] + bvv));
        *(ushort4*)(C + ((size_t)((b * NH + h) * NHD + d)) * NL + ls) = u;
      }
  }
}

// ---------------- output projection GEMM (64x128 tile, f32 out) ----------------
__global__ __launch_bounds__(256) void gemm_out(
    const __bf16* __restrict__ A, const __bf16* __restrict__ Bt,
    const float* __restrict__ bias, float* __restrict__ C) {
  __shared__ __bf16 As[64 * 64];
  __shared__ __bf16 Bs[128 * 64];
  const int tid = threadIdx.x;
  const int lane = tid & 63;
  const int wave = tid >> 6;
  const int nbm = (NB * NL) >> 6;
  const int bm = blockIdx.x % nbm;
  const int bn = blockIdx.x / nbm;
  const int wm = (wave >> 1) * 32;
  const int wn = (wave & 1) * 64;
  f32x4 acc[2][4] = {};
  const __bf16* Abase = A + (size_t)(bm * 64) * ND;
  const __bf16* Bbase = Bt + (size_t)(bn * 128) * ND;

  for (int kt = 0; kt < ND; kt += 64) {
#pragma unroll
    for (int i = 0; i < 2; i++) {
      int lin = i * 256 + tid;
      int row = lin >> 3;
      int c = (lin & 7) ^ (row & 7);
      gload16(Abase + (size_t)row * ND + kt + c * 8, (char*)As + lin * 16);
    }
#pragma unroll
    for (int i = 0; i < 4; i++) {
      int lin = i * 256 + tid;
      int row = lin >> 3;
      int c = (lin & 7) ^ (row & 7);
      gload16(Bbase + (size_t)row * ND + kt + c * 8, (char*)Bs + lin * 16);
    }
    __syncthreads();
#pragma unroll
    for (int kk = 0; kk < 2; kk++) {
      const int cb = kk * 4 + (lane >> 4);
      bf16x8 af[2], bfr[4];
#pragma unroll
      for (int mf = 0; mf < 2; mf++) {
        int rr = wm + mf * 16 + (lane & 15);
        af[mf] = *(const bf16x8*)((const char*)As + rr * 128 + ((cb ^ (rr & 7)) << 4));
      }
#pragma unroll
      for (int nf = 0; nf < 4; nf++) {
        int rr = wn + nf * 16 + (lane & 15);
        bfr[nf] = *(const bf16x8*)((const char*)Bs + rr * 128 + ((cb ^ (rr & 7)) << 4));
      }
      __builtin_amdgcn_s_setprio(1);
#pragma unroll
      for (int mf = 0; mf < 2; mf++)
#pragma unroll
        for (int nf = 0; nf < 4; nf++)
          acc[mf][nf] = __builtin_amdgcn_mfma_f32_16x16x32_bf16(af[mf], bfr[nf],
                                                                acc[mf][nf], 0, 0, 0);
      __builtin_amdgcn_s_setprio(0);
    }
    __syncthreads();
  }

  const int rbase = (lane >> 4) << 2;
  const int cbase = lane & 15;
#pragma unroll
  for (int mf = 0; mf < 2; mf++)
#pragma unroll
    for (int nf = 0; nf < 4; nf++) {
      int m0 = bm * 64 + wm + mf * 16 + rbase;
      int n = bn * 128 + wn + nf * 16 + cbase;
      float bvv = bias[n];
#pragma unroll
      for (int j = 0; j < 4; j++)
        C[(size_t)(m0 + j) * ND + n] = acc[mf][nf][j] + bvv;
    }
}

// ---------------- flash attention v3: 8 waves, dbuf K/V, counted vmcnt ----------
// 256 q-rows per block (wave w owns q0=qt*256+w*32, 2 qh subtiles), k-split 2.
__global__ __launch_bounds__(512, 4) void attn_kernel(
    const __bf16* __restrict__ Q, const __bf16* __restrict__ K,
    const __bf16* __restrict__ Vt, const unsigned char* __restrict__ bins,
    const float* __restrict__ emb, float* __restrict__ O0,
    float* __restrict__ O1, float* __restrict__ lsums) {
  __shared__ __bf16 Ks[2][64 * 64];
  __shared__ __bf16 Vs[2][64 * 64];
  __shared__ __bf16 Ps[8][32 * 64];
  __shared__ float embl2[33];
  const int tid = threadIdx.x;
  const int lane = tid & 63;
  const int wave = tid >> 6;               // 0..7
  const int qt = blockIdx.x & 7;           // q-tile of 256 rows
  const int h = (blockIdx.x >> 3) & 15;
  const int b = (blockIdx.x >> 7) & 1;
  const int s = blockIdx.x >> 8;           // k-split half
  if (tid < 33) embl2[tid] = emb[tid * NH + h] * 1.44269504f;
  const int lr = lane & 15;
  const int lg = lane >> 4;
  const int q0 = qt * 256 + wave * 32;
  const int bh = b * NH + h;

  // Q fragments: [kk][qh]
  const __bf16* Qb0 = Q + ((size_t)(bh * NL + q0 + lr)) * NHD + lg * 8;
  bf16x8 qf[2][2];
  qf[0][0] = *(const bf16x8*)(Qb0);
  qf[1][0] = *(const bf16x8*)(Qb0 + 32);
  qf[0][1] = *(const bf16x8*)(Qb0 + 16 * NHD);
  qf[1][1] = *(const bf16x8*)(Qb0 + 16 * NHD + 32);

  const unsigned char* binq0 =
      bins + ((size_t)b * NL + (q0 + lr)) * NL + s * 1024 + lg * 4;
  const unsigned char* binq1 = binq0 + (size_t)16 * NL;

  float lsum[2] = {0.f, 0.f};
  f32x4 oacc[4][2] = {};
  const __bf16* Kbase = K + ((size_t)(bh * NL + s * 1024)) * NHD;
  const __bf16* Vbase = Vt + ((size_t)(bh * NHD)) * NL + s * 1024;
  char* psw = (char*)&Ps[wave][0];
  const int pswz = (lr & 7) << 4;

  // 512 threads: 1 K-load + 1 V-load per thread per tile
#define STAGE(bufi, ktt)                                                        \
  {                                                                             \
    int row = tid >> 3;                                                         \
    int c = (tid & 7) ^ (row & 7);                                              \
    gload16(Kbase + (size_t)((ktt) + row) * NHD + c * 8,                        \
            (char*)&Ks[bufi][0] + tid * 16);                                    \
    gload16(Vbase + (size_t)row * NL + (ktt) + c * 8,                           \
            (char*)&Vs[bufi][0] + tid * 16);                                    \
  }

#define LOADBINS(dst, ktt)                                                      \
  {                                                                             \
    _Pragma("unroll") for (int kf = 0; kf < 4; kf++) {                          \
      dst[kf][0] = *(const uint32_t*)(binq0 + (ktt) + kf * 16);                 \
      dst[kf][1] = *(const uint32_t*)(binq1 + (ktt) + kf * 16);                 \
    }                                                                           \
  }

  uint32_t bcur[4][2], bnxt[4][2];
  STAGE(0, 0);
  LOADBINS(bcur, 0);
  __syncthreads();  // full drain: prologue staging + embl2 visible

  const int NT = 16;
  for (int t = 0; t < NT; t++) {
    const int kt = t * 64;
    __builtin_amdgcn_s_barrier();  // A: all waves done reading buf[(t+1)&1]
    if (t + 1 < NT) {
      STAGE((t + 1) & 1, kt + 64);
      asm volatile("s_waitcnt vmcnt(2)" ::: "memory");  // tile-t staging landed
    } else {
      asm volatile("s_waitcnt vmcnt(0)" ::: "memory");
    }
    __builtin_amdgcn_s_barrier();  // B: tile t visible to all waves
    if (t + 1 < NT) LOADBINS(bnxt, kt + 64);

    const int cur = t & 1;
    // QK^T + softmax in kf-pairs
#pragma unroll
    for (int kfp = 0; kfp < 2; kfp++) {
      f32x4 sacc[2][2] = {};
#pragma unroll
      for (int kk = 0; kk < 2; kk++) {
        const int cb = kk * 4 + lg;
        bf16x8 kb[2];
#pragma unroll
        for (int k2 = 0; k2 < 2; k2++) {
          int rr = (kfp * 2 + k2) * 16 + lr;
          kb[k2] = *(const bf16x8*)((const char*)&Ks[cur][0] + rr * 128 +
                                    ((cb ^ (rr & 7)) << 4));
        }
        __builtin_amdgcn_s_setprio(1);
#pragma unroll
        for (int qh = 0; qh < 2; qh++)
#pragma unroll
          for (int k2 = 0; k2 < 2; k2++)
            sacc[k2][qh] = __builtin_amdgcn_mfma_f32_16x16x32_bf16(
                kb[k2], qf[kk][qh], sacc[k2][qh], 0, 0, 0);
        __builtin_amdgcn_s_setprio(0);
      }
#pragma unroll
      for (int k2 = 0; k2 < 2; k2++) {
        const int kf = kfp * 2 + k2;
#pragma unroll
        for (int qh = 0; qh < 2; qh++) {
          float p[4];
#pragma unroll
          for (int j = 0; j < 4; j++) {
            int bin = (bcur[kf][qh] >> (8 * j)) & 255;
            p[j] = __builtin_amdgcn_exp2f(
                fmaf(sacc[k2][qh][j], 0.1803368801f, embl2[bin]));
            lsum[qh] += p[j];
          }
          ushort4 u;
          u.x = __builtin_bit_cast(unsigned short, (__bf16)p[0]);
          u.y = __builtin_bit_cast(unsigned short, (__bf16)p[1]);
          u.z = __builtin_bit_cast(unsigned short, (__bf16)p[2]);
          u.w = __builtin_bit_cast(unsigned short, (__bf16)p[3]);
          int row = qh * 16 + lr;
          int col = (kf * 32 + lg * 8) ^ pswz;
          *(ushort4*)(psw + row * 128 + col) = u;
        }
      }
    }

    // PV: vb shared across both q-halves
#pragma unroll
    for (int kk = 0; kk < 2; kk++) {
      const int cb = kk * 4 + lg;
      bf16x8 vb[4];
#pragma unroll
      for (int df = 0; df < 4; df++) {
        int rr = df * 16 + lr;
        vb[df] = *(const bf16x8*)((const char*)&Vs[cur][0] + rr * 128 +
                                  ((cb ^ (rr & 7)) << 4));
      }
      bf16x8 pa[2];
#pragma unroll
      for (int qh = 0; qh < 2; qh++)
        pa[qh] = *(const bf16x8*)(psw + (qh * 16 + lr) * 128 +
                                  ((kk * 64 + lg * 16) ^ pswz));
      __builtin_amdgcn_s_setprio(1);
#pragma unroll
      for (int qh = 0; qh < 2; qh++)
#pragma unroll
        for (int df = 0; df < 4; df++)
          oacc[df][qh] = __builtin_amdgcn_mfma_f32_16x16x32_bf16(
              vb[df], pa[qh], oacc[df][qh], 0, 0, 0);
      __builtin_amdgcn_s_setprio(0);
    }

#pragma unroll
    for (int kf = 0; kf < 4; kf++)
#pragma unroll
      for (int qh = 0; qh < 2; qh++) bcur[kf][qh] = bnxt[kf][qh];
  }

  // epilogue: unnormalized O + lsum partials for this k-half
  float* Op = s ? O1 : O0;
  float* lsp = lsums + s * BHNL;
#pragma unroll
  for (int qh = 0; qh < 2; qh++) {
    float l = lsum[qh];
    l += __shfl_xor(l, 16, 64);
    l += __shfl_xor(l, 32, 64);
    int qrow = q0 + qh * 16 + lr;
    size_t r = (size_t)bh * NL + qrow;
    if (lg == 0) lsp[r] = l;
    float* ob = Op + r * NHD + lg * 4;
#pragma unroll
    for (int df = 0; df < 4; df++) *(f32x4*)(ob + df * 16) = oacc[df][qh];
  }
#undef STAGE
#undef LOADBINS
}

// ---------------- combine: O = (O0+O1)/(l0+l1), write bf16 [b,l,h*d] ------------
__global__ __launch_bounds__(256) void combine_kernel(
    const float* __restrict__ O0, const float* __restrict__ O1,
    const float* __restrict__ ls, __bf16* __restrict__ outb) {
  int gid = blockIdx.x * 256 + threadIdx.x;  // BHNL*16 threads
  int row = gid >> 4;
  int d4 = (gid & 15) << 2;
  float l = ls[row] + ls[BHNL + row];
  float inv = 1.0f / l;
  f32x4 a = *(const f32x4*)(O0 + (size_t)row * NHD + d4);
  f32x4 c = *(const f32x4*)(O1 + (size_t)row * NHD + d4);
  int bh = row >> 11, q = row & (NL - 1);
  int b = bh >> 4, h = bh & 15;
  ushort4 u;
  u.x = __builtin_bit_cast(unsigned short, (__bf16)((a[0] + c[0]) * inv));
  u.y = __builtin_bit_cast(unsigned short, (__bf16)((a[1] + c[1]) * inv));
  u.z = __builtin_bit_cast(unsigned short, (__bf16)((a[2] + c[2]) * inv));
  u.w = __builtin_bit_cast(unsigned short, (__bf16)((a[3] + c[3]) * inv));
  *(ushort4*)(outb + ((size_t)(b * NL + q)) * ND + h * NHD + d4) = u;
}

extern "C" void kernel_launch(void* const* d_in, const int* in_sizes, int n_in,
                              void* d_out, int out_size, void* d_ws, size_t ws_size,
                              hipStream_t stream) {
  const float* query = (const float*)d_in[0];
  const float* key = (const float*)d_in[1];
  const float* value = (const float*)d_in[2];
  const float* pos = (const float*)d_in[3];
  const float* Wq = (const float*)d_in[4];
  const float* bq = (const float*)d_in[5];
  const float* Wk = (const float*)d_in[6];
  const float* bk = (const float*)d_in[7];
  const float* Wv = (const float*)d_in[8];
  const float* bv = (const float*)d_in[9];
  const float* Wo = (const float*)d_in[10];
  const float* bo = (const float*)d_in[11];
  const float* emb = (const float*)d_in[12];

  if (ws_size < (64ull << 20)) return;  // need 64MB scratch
  char* ws = (char*)d_ws;
  const size_t MB = 1ull << 20;
  __bf16* qb = (__bf16*)(ws + 0 * MB);
  __bf16* kb = (__bf16*)(ws + 8 * MB);
  __bf16* vb = (__bf16*)(ws + 16 * MB);
  __bf16* Wq_t = (__bf16*)(ws + 24 * MB);
  __bf16* Wk_t = (__bf16*)(ws + 26 * MB);
  __bf16* Wv_t = (__bf16*)(ws + 28 * MB);
  __bf16* Wo_t = (__bf16*)(ws + 30 * MB);
  __bf16* Qp = (__bf16*)(ws + 32 * MB);
  __bf16* Kp = (__bf16*)(ws + 40 * MB);
  __bf16* Vtp = (__bf16*)(ws + 48 * MB);
  unsigned char* binsb = (unsigned char*)(ws + 56 * MB);
  // after gemm_qkv, qb/kb (0-16MB) and Wq_t (24-26MB) are dead:
  float* Opart0 = (float*)(ws + 0 * MB);       // 16MB f32, over qb+kb
  float* Opart1 = (float*)d_out;               // 16MB f32, free until gemm_out
  float* lsums = (float*)(ws + 24 * MB);       // 2*BHNL f32 = 512KB, over Wq_t
  __bf16* attnb = (__bf16*)(ws + 16 * MB);     // 8MB bf16, over vb (dead post-qkv)

  const int n4 = NB * NL * ND / 4;
  cvt3_f32_bf16<<<dim3(n4 / 256, 3), 256, 0, stream>>>(query, key, value, qb, kb, vb,
                                                       n4);
  transpose_cvt4<<<dim3(32, 32, 4), dim3(32, 8), 0, stream>>>(Wq, Wk, Wv, Wo, Wq_t,
                                                              Wk_t, Wv_t, Wo_t);
  bins_kernel<<<dim3(NL / 1024, NL, NB), 256, 0, stream>>>(pos, binsb);

  gemm_qkv<<<3 * 256, 256, 0, stream>>>(qb, kb, vb, Wq_t, Wk_t, Wv_t, bq, bk, bv, Qp,
                                        Kp, Vtp);

  attn_kernel<<<512, 512, 0, stream>>>(Qp, Kp, Vtp, binsb, emb, Opart0, Opart1,
                                       lsums);

  combine_kernel<<<(BHNL * 16) / 256, 256, 0, stream>>>(Opart0, Opart1, lsums, attnb);

  gemm_out<<<((NB * NL) / 64) * (ND / 128), 256, 0, stream>>>(attnb, Wo_t, bo,
                                                              (float*)d_out);
}